// Round 9
// baseline (164.479 us; speedup 1.0000x reference)
//
#include <hip/hip_runtime.h>

// Problem constants: x [B=1,T=8,C=32,D=32,H=64,W=64] fp32
constexpr int NT = 8;    // B*T
constexpr int C  = 32;
constexpr int D  = 32;
constexpr int H  = 64;
constexpr int W  = 64;   // == wavefront size: W-conv via lane shuffles
constexpr int ROWS = 4;  // output rows per block
constexpr int SP = D * H * W;       // per-channel spatial size = 131072
constexpr int HW = H * W;           // d-plane stride = 4096 elements
constexpr int CH_PER_BLK = 16;      // channels iterated per block

typedef unsigned int u32;

// global -> LDS direct copy, 4B per lane (wave-uniform LDS base + lane*4)
#define GLD_TO_LDS(gp, lp)                                              \
    __builtin_amdgcn_global_load_lds(                                   \
        (const __attribute__((address_space(1))) void*)(gp),            \
        (__attribute__((address_space(3))) void*)(lp), 4, 0, 0)

// bf16 RNE pack / unpack (validated round 3)
static __device__ __forceinline__ u32 f2bf(float f) {
    u32 u = __float_as_uint(f);
    return (u + 0x7fffu + ((u >> 16) & 1u)) >> 16;
}
static __device__ __forceinline__ float bf_lo(u32 v) { return __uint_as_float(v << 16); }
static __device__ __forceinline__ float bf_hi(u32 v) { return __uint_as_float(v & 0xffff0000u); }

// ---------------------------------------------------------------------------
// Kernel A: depthwise chain, channel-pipelined with double-buffered LDS.
//   h = zconv3(x)+bz ; h = hconv3(h)+bx ; h = wconv3(h)+by ; 3x: h = zconv5_dil2(h)+bs
// h is stored PACKED bf16x2 (d-pairs) into workspace for kernel B.
//
// Structure: grid = 8n x 16htile x 2chalf = 256 blocks (1 per CU), 256 thr.
// Per block: iterate 16 channels; while computing channel c from LDS buffer
// cur, stage channel c+1 into buffer cur^1 via global_load_lds (no register
// destinations -> cannot be sunk; a full channel's compute (~1500 cyc)
// covers the load latency IN-WAVE — no reliance on cross-wave overlap,
// which rounds 3/5/8 proved doesn't materialize).
// Race-freedom of the single barrier/iter: stage target buffer is the one
// every wave finished reading before the barrier it just passed.
//
// Boundary bias semantics: a later conv's out-of-image tap drops its whole
// term (incl. earlier biases) — clamped source row + zeroed tap weight
// (term enters as wxk*(zconv+bz), so wxk=0 is exact).
// ---------------------------------------------------------------------------
__global__ __launch_bounds__(256)
void dw_chain(const float* __restrict__ x,
              const float* __restrict__ w0z, const float* __restrict__ b0z,
              const float* __restrict__ w0x, const float* __restrict__ b0x,
              const float* __restrict__ w0y, const float* __restrict__ b0y,
              const float* __restrict__ wsz, const float* __restrict__ bsz,
              u32* __restrict__ hws)
{
    extern __shared__ float smem[];   // [2][6][32][64] f32 = 98304 B

    // XCD swizzle: 256 blocks round-robin over 8 XCDs -> n = rr&7 gives each
    // XCD one n; adjacent htile blocks (same XCD) share halo rows in L2.
    const int rr    = blockIdx.x;
    const int n     = rr & 7;
    const int htile = (rr >> 3) & 15;
    const int chalf = rr >> 7;            // 0..1
    const int h0    = htile * ROWS;
    const int c0    = chalf * CH_PER_BLK;

    const int tid = threadIdx.x;
    const int w   = tid & 63;                                   // lane
    const int r   = __builtin_amdgcn_readfirstlane(tid >> 6);   // wave 0..3 (SGPR)
    const int hg  = h0 + r;               // this wave's output row

    // ---- stage channel c into LDS buffer buf: [6 rows][32 d][64 w] -------
    auto stage = [&](int buf, int c) {
        const float* xc = x + ((size_t)n * C + c) * SP;
        float* sb = smem + buf * (6 * D * W);
        #pragma unroll 1
        for (int t = r; t < 6 * D; t += 4) {       // t scalar (r is SGPR)
            const int j = t >> 5;                  // halo row 0..5
            const int d = t & 31;                  // d-plane
            int hr = h0 - 1 + j;
            hr = (hr < 0) ? 0 : ((hr > H - 1) ? H - 1 : hr);
            GLD_TO_LDS(xc + (size_t)d * HW + (size_t)hr * W + w,
                       sb + (j * D + d) * W);
        }
    };

    stage(0, c0);                         // prologue
    int cur = 0;

    #pragma unroll 1
    for (int ci = 0; ci < CH_PER_BLK; ++ci) {
        const int c = c0 + ci;

        asm volatile("s_waitcnt vmcnt(0)" ::: "memory");  // buf 'cur' staged
        __syncthreads();                                  // ...for ALL waves

        if (ci + 1 < CH_PER_BLK) stage(cur ^ 1, c + 1);   // prefetch next ch
        __builtin_amdgcn_sched_barrier(0);                // stage issues first

        // Per-channel weights (block-uniform -> scalar regs)
        const float wz0 = w0z[c*3+0], wz1 = w0z[c*3+1], wz2 = w0z[c*3+2];
        const float wx1 = w0x[c*3+1];
        const float wy0 = w0y[c*3+0], wy1 = w0y[c*3+1], wy2 = w0y[c*3+2];
        const float bz = b0z[c], bx = b0x[c], by = b0y[c], bs = bsz[c];
        float wsk[5];
        #pragma unroll
        for (int k = 0; k < 5; ++k) wsk[k] = wsz[c*5+k];

        // Boundary: tap weight zeroed at image edge (clamped LDS row benign)
        const float wxk0 = (hg > 0)     ? w0x[c*3+0] : 0.f;
        const float wxk2 = (hg < H - 1) ? w0x[c*3+2] : 0.f;

        const float* sb = smem + cur * (6 * D * W);

        // h-conv (along H) from LDS: wave r uses halo rows r, r+1, r+2
        float hrow[D];
        #pragma unroll
        for (int d = 0; d < D; ++d) {
            const float a0 = sb[((r    ) * D + d) * W + w];
            const float a1 = sb[((r + 1) * D + d) * W + w];
            const float a2 = sb[((r + 2) * D + d) * W + w];
            hrow[d] = wxk0 * a0 + wx1 * a1 + wxk2 * a2;
        }

        // z-conv (along D) + folded biases
        const float cb = bx + (wxk0 + wx1 + wxk2) * bz;
        float acc2[D];
        #pragma unroll
        for (int d = 0; d < D; ++d) {
            float t = cb + wz1 * hrow[d];
            if (d > 0)     t += wz0 * hrow[d - 1];
            if (d < D - 1) t += wz2 * hrow[d + 1];
            acc2[d] = t;
        }

        // w-conv via lane shuffles (W == 64 == wavefront)
        const bool has_l = (w > 0), has_r = (w < W - 1);
        float acc3[D];
        #pragma unroll
        for (int d = 0; d < D; ++d) {
            float left  = __shfl_up(acc2[d], 1);
            float right = __shfl_down(acc2[d], 1);
            float t = by + wy1 * acc2[d];
            if (has_l) t += wy0 * left;
            if (has_r) t += wy2 * right;
            acc3[d] = t;
        }

        // three 5-tap dilation-2 convs along D (pad 4), in registers
        #pragma unroll
        for (int it = 0; it < 3; ++it) {
            float s[D];
            #pragma unroll
            for (int d = 0; d < D; ++d) {
                float t = bs;
                #pragma unroll
                for (int k = 0; k < 5; ++k) {
                    int j = d + 2 * k - 4;
                    if (j >= 0 && j < D) t += wsk[k] * acc3[j];
                }
                s[d] = t;
            }
            #pragma unroll
            for (int d = 0; d < D; ++d) acc3[d] = s[d];
        }

        // store packed bf16 d-pairs: hws[((n*C+c)*(D/2)+k)*HW + hg*W + w]
        u32* hc = hws + (((size_t)n * C + c) * (D / 2)) * HW
                      + (size_t)hg * W + w;
        #pragma unroll
        for (int k = 0; k < D / 2; ++k)
            hc[(size_t)k * HW] = f2bf(acc3[2*k]) | (f2bf(acc3[2*k+1]) << 16);

        cur ^= 1;
    }
}

// ---------------------------------------------------------------------------
// Kernel B: pointwise 1x1x1 conv over channels + residual multiply.
// Reads packed-bf16 h (2 d-planes per thread, 4B coalesced), f32 x;
// writes f32 out. Round-3 phase-B logic (numerically validated).
// ---------------------------------------------------------------------------
__global__ __launch_bounds__(256)
void pw_mul(const float* __restrict__ x,
            const u32* __restrict__ hws,
            const float* __restrict__ wp, const float* __restrict__ bp,
            float* __restrict__ out)
{
    const int pid  = blockIdx.x * 256 + threadIdx.x;   // (n, dp, h, w)
    const int n    = pid >> 16;                        // / (16*4096)
    const int dp   = (pid >> 12) & 15;                 // d-pair
    const int sphw = pid & 4095;                       // h*64+w

    const u32* hp = hws + ((size_t)(n * C) * (D / 2) + dp) * HW + sphw;

    float v0[C], v1[C];
    #pragma unroll
    for (int ci = 0; ci < C; ++ci) {
        const u32 u = hp[(size_t)ci * (D / 2) * HW];
        v0[ci] = bf_lo(u);
        v1[ci] = bf_hi(u);
    }

    const size_t i0 = (size_t)n * C * SP + (size_t)(2 * dp) * HW + sphw;

    for (int co = 0; co < C; ++co) {
        float y0 = bp[co], y1 = bp[co];
        #pragma unroll
        for (int ci = 0; ci < C; ++ci) {
            const float wv = wp[co * C + ci];
            y0 += wv * v0[ci];
            y1 += wv * v1[ci];
        }
        const size_t ia = i0 + (size_t)co * SP;
        const size_t ib = ia + (size_t)HW;
        out[ia] = x[ia] * y0;
        out[ib] = x[ib] * y1;
    }
}

extern "C" void kernel_launch(void* const* d_in, const int* in_sizes, int n_in,
                              void* d_out, int out_size, void* d_ws, size_t ws_size,
                              hipStream_t stream)
{
    const float* x   = (const float*)d_in[0];
    const float* w0z = (const float*)d_in[1];
    const float* b0z = (const float*)d_in[2];
    const float* w0x = (const float*)d_in[3];
    const float* b0x = (const float*)d_in[4];
    const float* w0y = (const float*)d_in[5];
    const float* b0y = (const float*)d_in[6];
    const float* wsz = (const float*)d_in[7];
    const float* bsz = (const float*)d_in[8];
    const float* wp  = (const float*)d_in[9];
    const float* bp  = (const float*)d_in[10];
    float* out = (float*)d_out;
    u32* hws = (u32*)d_ws;               // 16.8M words = 67 MB (ws >= ~384 MB)

    // Kernel A: depthwise chain -> packed bf16 h in workspace
    const int gridA = NT * (H / ROWS) * (C / CH_PER_BLK);   // 8*16*2 = 256
    dw_chain<<<gridA, 256, 2 * 6 * D * W * sizeof(float), stream>>>(
        x, w0z, b0z, w0x, b0x, w0y, b0y, wsz, bsz, hws);

    // Kernel B: pointwise + residual -> out
    const int gridB = NT * (D / 2) * HW / 256;              // 2048
    pw_mul<<<gridB, 256, 0, stream>>>(x, hws, wp, bp, out);
}